// Round 3
// baseline (151.234 us; speedup 1.0000x reference)
//
#include <hip/hip_runtime.h>

// Problem constants (fixed-shape problem)
#define BB 4
#define CC 16
#define KK 16
#define HWP (512 * 512)
#define THREADS 256               // 4 waves per block
#define TPW 128                   // pixels per wave (4 MFMA groups of 32)
#define TPB ((THREADS / 64) * TPW)  // 512 pixels per block
#define NTILES (HWP / TPB)        // 512 tiles per batch -> 2048 blocks
#define NGROUP (TPW / 32)         // 4
#define NWAVE (THREADS / 64)      // 4
#define NSLICE 16                 // atomic contention slices
#define WSTOT (64 + 1024 + 1024)  // floats per slice: cnt | sum | sq

typedef short bf16x8 __attribute__((ext_vector_type(8)));   // 8 bf16 (4 VGPRs)
typedef float f32x4 __attribute__((ext_vector_type(4)));    // MFMA C/D

__device__ __forceinline__ float fmaxf_(float a, float b) { return a > b ? a : b; }

// fp32 -> bf16 round-to-nearest-even (bit trick; no NaN in this data)
__device__ __forceinline__ unsigned short f2bf(float f) {
    unsigned u = __float_as_uint(f);
    u += 0x7FFFu + ((u >> 16) & 1u);
    return (unsigned short)(u >> 16);
}
__device__ __forceinline__ unsigned pkbf(float x, float y) {
    return (unsigned)f2bf(x) | ((unsigned)f2bf(y) << 16);
}

// Round-12: MLP play (round-2 post-mortem: 2x waves at 32 VGPR was neutral —
// per-wave in-flight loads, not wave count, is the limiter).
//  - THREADS 512->256 but keep TPW=128: grid 1024->2048 blocks (8/CU, finer
//    tail granularity; Occupancy was 55% time-avg due to one-generation tail).
//  - __launch_bounds__(256, 4): VGPR cap 128 (16 waves/CU — round 2 proved
//    32 waves/CU buys nothing over 16).
//  - ALL 24 loads issued before any consume: mask int2 x16 into a register
//    array, emb float4 x8 hoisted ahead of the bit-combine. ~16 KB in flight
//    per wave vs ~1-2 KB when the allocator was squeezed to 32 VGPR.
//  - per rounds 8-9: NO sched_barrier / manual prefetch games beyond load
//    hoisting; compiler schedules the vmcnt counts itself.
__global__ __launch_bounds__(THREADS, 4) void disc_mfma_kernel(
    const float* __restrict__ emb, const int* __restrict__ masks,
    float* __restrict__ ws)   // NSLICE slices of [cnt 64 | sum 1024 | sq 1024]
{
    __shared__ __align__(16) unsigned short bits[TPB];  // 1 KB, per-wave regions
    __shared__ float redbuf[NWAVE][64][9];   // pad 8->9: conflict-light reduce
    __shared__ float cnt_red[NWAVE][16];

    const int tid = threadIdx.x;
    const int lane = tid & 63;
    const int wave = tid >> 6;
    const int b = blockIdx.x / NTILES;
    const int tile = blockIdx.x % NTILES;
    const size_t base_px = (size_t)tile * TPB + wave * TPW;

    const int quad = lane >> 4;     // 0..3
    const int r = lane & 15;        // A-row (mask idx) == B-col (channel idx)

    // ---- issue ALL loads first: 16 mask int2 + 8 emb float4 per lane ----
    const int* mbase = masks + (size_t)b * KK * HWP + base_px + 2 * lane;
    int2 mm[KK];
    #pragma unroll
    for (int k = 0; k < KK; ++k) {
        mm[k] = *(const int2*)(mbase + (size_t)k * HWP);
    }

    const float* ebase = emb + ((size_t)b * CC + r) * HWP + base_px;  // channel r
    float4 ef[NGROUP][2];
    #pragma unroll
    for (int g = 0; g < NGROUP; ++g) {
        const float4* ep = (const float4*)(ebase + g * 32 + quad * 8);
        ef[g][0] = ep[0];
        ef[g][1] = ep[1];
    }

    // ---- combine mask bits (consumes mm[] in issue order) ----
    unsigned v0 = 0, v1 = 0;
    #pragma unroll
    for (int k = 0; k < KK; ++k) {
        v0 |= (mm[k].x > 0 ? 1u : 0u) << k;
        v1 |= (mm[k].y > 0 ? 1u : 0u) << k;
    }
    ((unsigned*)bits)[wave * (TPW / 2) + lane] = v0 | (v1 << 16);  // px base+2*lane, +1
    // no barrier: this wave reads only bits[wave*TPW .. +127], written above
    // by its own lanes (DS ops wave-ordered; compiler emits the lgkmcnt wait)

    // ---- phase 2: 4 groups of 32 px; 3 MFMAs each ----
    union { bf16x8 v; unsigned short s[8]; } Bones;
    #pragma unroll
    for (int i = 0; i < 8; ++i) Bones.s[i] = 0x3F80;   // bf16 1.0

    f32x4 acc_s = {0.f, 0.f, 0.f, 0.f};
    f32x4 acc_q = {0.f, 0.f, 0.f, 0.f};
    f32x4 acc_c = {0.f, 0.f, 0.f, 0.f};

    #pragma unroll
    for (int g = 0; g < NGROUP; ++g) {
        const int p0 = wave * TPW + g * 32;

        // A-frag: mask bit r of pixels p0+quad*8..+7 (16B LDS read, 4-lane bcast)
        uint4 bw = *(const uint4*)&bits[p0 + quad * 8];
        union { bf16x8 v; unsigned u[4]; } A;
        A.u[0] = ((bw.x >> r) & 0x00010001u) * 0x3F80u;
        A.u[1] = ((bw.y >> r) & 0x00010001u) * 0x3F80u;
        A.u[2] = ((bw.z >> r) & 0x00010001u) * 0x3F80u;
        A.u[3] = ((bw.w >> r) & 0x00010001u) * 0x3F80u;

        // B-frags: channel r, pixels g*32+quad*8..+7 (already in registers)
        float4 f0 = ef[g][0], f1 = ef[g][1];
        union { bf16x8 v; unsigned u[4]; } Bf, B2;
        Bf.u[0] = pkbf(f0.x, f0.y);
        Bf.u[1] = pkbf(f0.z, f0.w);
        Bf.u[2] = pkbf(f1.x, f1.y);
        Bf.u[3] = pkbf(f1.z, f1.w);
        B2.u[0] = pkbf(f0.x * f0.x, f0.y * f0.y);
        B2.u[1] = pkbf(f0.z * f0.z, f0.w * f0.w);
        B2.u[2] = pkbf(f1.x * f1.x, f1.y * f1.y);
        B2.u[3] = pkbf(f1.z * f1.z, f1.w * f1.w);

        acc_s = __builtin_amdgcn_mfma_f32_16x16x32_bf16(A.v, Bf.v, acc_s, 0, 0, 0);
        acc_q = __builtin_amdgcn_mfma_f32_16x16x32_bf16(A.v, B2.v, acc_q, 0, 0, 0);
        acc_c = __builtin_amdgcn_mfma_f32_16x16x32_bf16(A.v, Bones.v, acc_c, 0, 0, 0);
    }

    // ---- block-level reduction (C/D: col=lane&15, row=quad*4+reg) ----
    #pragma unroll
    for (int j = 0; j < 4; ++j) {
        redbuf[wave][lane][j] = acc_s[j];
        redbuf[wave][lane][4 + j] = acc_q[j];
    }
    if (r == 0) {   // count cols identical; col-0 lanes own rows quad*4..+3
        #pragma unroll
        for (int reg = 0; reg < 4; ++reg) cnt_red[wave][quad * 4 + reg] = acc_c[reg];
    }
    __syncthreads();

    float* slice = ws + (size_t)(blockIdx.x & (NSLICE - 1)) * WSTOT;
    #pragma unroll
    for (int t = 0; t < 2; ++t) {
        const int fi = tid + t * THREADS;          // 0..511
        const int l2 = fi >> 3, j = fi & 7;
        float v = 0.f;
        #pragma unroll
        for (int w = 0; w < NWAVE; ++w) v += redbuf[w][l2][j];
        const int reg = j & 3, isq = j >> 2;
        const int krow = (l2 >> 4) * 4 + reg;
        const int ccol = l2 & 15;
        atomicAdd(&slice[64 + isq * 1024 + ((size_t)b * KK + krow) * CC + ccol], v);
    }
    if (tid < KK) {
        float ctot = 0.f;
        #pragma unroll
        for (int w = 0; w < NWAVE; ++w) ctot += cnt_red[w][tid];
        atomicAdd(&slice[b * KK + tid], ctot);
    }
}

__global__ __launch_bounds__(1024) void disc_finalize_kernel(
    const float* __restrict__ ws, float* __restrict__ out)
{
    __shared__ float red[WSTOT];             // slice-reduced [cnt|sum|sq]
    __shared__ float means[BB][KK][CC];
    __shared__ float partial[BB];
    const int tid = threadIdx.x;

    // vectorized slice reduction: 528 float4, 16 independent loads each
    for (int i4 = tid; i4 < WSTOT / 4; i4 += 1024) {
        float4 t = {0.f, 0.f, 0.f, 0.f};
        #pragma unroll
        for (int s = 0; s < NSLICE; ++s) {
            float4 v = *(const float4*)(ws + (size_t)s * WSTOT + 4 * i4);
            t.x += v.x; t.y += v.y; t.z += v.z; t.w += v.w;
        }
        *(float4*)(red + 4 * i4) = t;
    }
    __syncthreads();

    const float* red_cnt = red;
    const float* red_sum = red + 64;
    const float* red_sq  = red + 64 + 1024;

    const int b = tid >> 6;       // one wave per batch (waves 0..3 active)
    const int lane = tid & 63;
    const bool active = tid < 256;

    const float DELTA_PULL = 0.5f;
    const float DELTA_PUSH = 1.5f;
    const float EPS = 1e-6f;

    unsigned long long bal = 0ull;
    float M = 0.f, pull_b = 0.f;

    if (active) {
        float cntk = 0.f;
        bool valid = false;
        float pull_k = 0.f;
        if (lane < KK) {
            int k = lane;
            cntk = red_cnt[b * KK + k];
            valid = cntk > 0.f;
            float safe = fmaxf_(cntk, 1.f);
            float acc_sq = 0.f, acc_ss = 0.f;
            #pragma unroll
            for (int c = 0; c < CC; ++c) {
                float sv = red_sum[(b * KK + k) * CC + c];
                means[b][k][c] = sv / safe;
                acc_sq += red_sq[(b * KK + k) * CC + c];
                acc_ss += sv * sv;
            }
            if (valid) pull_k = (acc_sq - acc_ss / cntk) / (cntk + EPS);
        }

        bal = __ballot(lane < KK && valid);
        M = (float)__popcll(bal);

        float ps = pull_k;
        #pragma unroll
        for (int d = 32; d >= 1; d >>= 1) ps += __shfl_xor(ps, d, 64);
        pull_b = ps / fmaxf_(M, 1.f);
    }

    __syncthreads();

    if (active) {
        float push = 0.f;
        for (int t = lane; t < KK * KK; t += 64) {
            int i = t >> 4, j = t & 15;
            if (i < j && ((bal >> i) & 1ull) && ((bal >> j) & 1ull)) {
                float d2 = 1e-12f;
                #pragma unroll
                for (int c = 0; c < CC; ++c) {
                    float df = means[b][i][c] - means[b][j][c];
                    d2 = fmaf(df, df, d2);
                }
                float dist = sqrtf(d2);
                float h = fmaxf_(DELTA_PUSH - dist, 0.f);
                push += h * h;
            }
        }
        #pragma unroll
        for (int d = 32; d >= 1; d >>= 1) push += __shfl_xor(push, d, 64);

        if (lane == 0) {
            float npairs = M * (M - 1.f) * 0.5f;
            float push_b = (M > 1.f) ? push / fmaxf_(npairs, 1.f) : 0.f;
            partial[b] = DELTA_PULL * pull_b + push_b;
        }
    }
    __syncthreads();
    if (tid == 0) {
        out[0] = (partial[0] + partial[1] + partial[2] + partial[3]) * 0.25f;
    }
}

extern "C" void kernel_launch(void* const* d_in, const int* in_sizes, int n_in,
                              void* d_out, int out_size, void* d_ws, size_t ws_size,
                              hipStream_t stream) {
    const float* emb = (const float*)d_in[0];
    const int* masks = (const int*)d_in[1];
    float* ws = (float*)d_ws;

    hipMemsetAsync(d_ws, 0, NSLICE * WSTOT * sizeof(float), stream);

    dim3 grid(BB * NTILES);
    disc_mfma_kernel<<<grid, THREADS, 0, stream>>>(emb, masks, ws);
    disc_finalize_kernel<<<1, 1024, 0, stream>>>(ws, (float*)d_out);
}

// Round 4
// 146.719 us; speedup vs baseline: 1.0308x; 1.0308x over previous
//
#include <hip/hip_runtime.h>

// Problem constants (fixed-shape problem)
#define BB 4
#define CC 16
#define KK 16
#define HWP (512 * 512)
#define THREADS 256               // 4 waves per block
#define TPW 128                   // pixels per wave (4 MFMA groups of 32)
#define TPB ((THREADS / 64) * TPW)  // 512 pixels per block
#define NTILES (HWP / TPB)        // 512 tiles per batch -> 2048 blocks
#define NGROUP (TPW / 32)         // 4
#define NWAVE (THREADS / 64)      // 4
#define NSLICE 16                 // atomic contention slices
#define WSTOT (64 + 1024 + 1024)  // floats per slice: cnt | sum | sq

typedef short bf16x8 __attribute__((ext_vector_type(8)));   // 8 bf16 (4 VGPRs)
typedef float f32x4 __attribute__((ext_vector_type(4)));    // MFMA C/D

__device__ __forceinline__ float fmaxf_(float a, float b) { return a > b ? a : b; }

// fp32 -> bf16 round-to-nearest-even (bit trick; no NaN in this data)
__device__ __forceinline__ unsigned short f2bf(float f) {
    unsigned u = __float_as_uint(f);
    u += 0x7FFFu + ((u >> 16) & 1u);
    return (unsigned short)(u >> 16);
}
__device__ __forceinline__ unsigned pkbf(float x, float y) {
    return (unsigned)f2bf(x) | ((unsigned)f2bf(y) << 16);
}

// async global->LDS, 16B per lane, linear LDS dest (wave-uniform base + lane*16)
__device__ __forceinline__ void gld16(const void* g, void* l) {
    __builtin_amdgcn_global_load_lds(
        (const __attribute__((address_space(1))) unsigned*)g,
        (__attribute__((address_space(3))) unsigned*)l, 16, 0, 0);
}

// Round-13: DMA play. Rounds 2-3 post-mortem: compiler pins VGPR to 32 and
// re-interleaves loads no matter what (hoisting defeated); per-wave in-flight
// bytes stuck below one wave-instruction -> latency-bound at 1.6 TB/s.
// Fix: global_load_lds width=16 staging (zero VGPR cost, fire-and-forget):
//  - per wave: 8 DMA instrs stage 16 mask planes (8 KB) + 8 stage 16 emb
//    channels (8 KB) into wave-private LDS; 16 KB in flight per wave, always.
//  - source-side XOR swizzle (chunk ^ (plane&7)) so fragment ds_read_b128
//    (16 lanes x same chunk of 16 planes) is bank-uniform (rule-21 pattern:
//    linear LDS dest + swizzled global source + swizzled read).
//  - bits[] bitpack phase eliminated; A-frags built from staged int32s.
//  - no barriers in hot path (wave-private regions); one s_waitcnt vmcnt(0)
//    + sched_barrier(0) fence before first ds_read (rule-18 insurance).
__global__ __launch_bounds__(THREADS) void disc_mfma_kernel(
    const float* __restrict__ emb, const int* __restrict__ masks,
    float* __restrict__ ws)   // NSLICE slices of [cnt 64 | sum 1024 | sq 1024]
{
    __shared__ __align__(16) int   mstage[NWAVE][KK][128];   // 32 KB
    __shared__ __align__(16) float estage[NWAVE][CC][128];   // 32 KB
    __shared__ float redbuf[NWAVE][64][9];   // pad 8->9: conflict-light reduce
    __shared__ float cnt_red[NWAVE][16];

    const int tid = threadIdx.x;
    const int lane = tid & 63;
    const int wave = tid >> 6;
    const int b = blockIdx.x / NTILES;
    const int tile = blockIdx.x % NTILES;
    const size_t base_px = (size_t)tile * TPB + wave * TPW;

    const int quad = lane >> 4;     // 0..3
    const int r = lane & 15;        // A-row (mask idx) == B-col (channel idx)

    // ---- stage: 16 async DMA instrs, 16 KB in flight per wave ----
    // instr j: lanes 0-31 -> plane 2j, lanes 32-63 -> plane 2j+1 (512B each)
    // LDS linear; global source pre-swizzled: chunk c_src = (l&31) ^ (k&7)
    const int l31 = lane & 31;
    const int khalf = lane >> 5;                 // 0 or 1
    const int* mplane = masks + (size_t)b * KK * HWP + base_px;
    const float* eplane = emb + (size_t)b * CC * HWP + base_px;
    #pragma unroll
    for (int j = 0; j < 8; ++j) {
        const int k = 2 * j + khalf;
        const unsigned soff = (unsigned)((l31 ^ (k & 7)) * 4);  // in elements (4B)
        gld16(mplane + (size_t)k * HWP + soff, &mstage[wave][2 * j][0]);
        gld16(eplane + (size_t)k * HWP + soff, &estage[wave][2 * j][0]);
    }

    asm volatile("s_waitcnt vmcnt(0)" ::: "memory");
    __builtin_amdgcn_sched_barrier(0);
    // no __syncthreads: each wave reads only its own mstage/estage region

    // ---- phase 2: 4 groups of 32 px; 3 MFMAs each ----
    union { bf16x8 v; unsigned short s[8]; } Bones;
    #pragma unroll
    for (int i = 0; i < 8; ++i) Bones.s[i] = 0x3F80;   // bf16 1.0

    f32x4 acc_s = {0.f, 0.f, 0.f, 0.f};
    f32x4 acc_q = {0.f, 0.f, 0.f, 0.f};
    f32x4 acc_c = {0.f, 0.f, 0.f, 0.f};

    const int rx = r & 7;   // read-side swizzle key for plane/channel r

    #pragma unroll
    for (int g = 0; g < NGROUP; ++g) {
        const int cbase = g * 8 + quad * 2;     // 16B-chunk index (4 px/chunk)

        // A-frag: mask plane r, px cbase*4 .. +7 (two swizzled b128 reads)
        int4 ma = *(const int4*)&mstage[wave][r][((cbase + 0) ^ rx) * 4];
        int4 mb = *(const int4*)&mstage[wave][r][((cbase + 1) ^ rx) * 4];
        union { bf16x8 v; unsigned u[4]; } A;
        A.u[0] = (ma.x > 0 ? 0x3F80u : 0u) | (ma.y > 0 ? 0x3F800000u : 0u);
        A.u[1] = (ma.z > 0 ? 0x3F80u : 0u) | (ma.w > 0 ? 0x3F800000u : 0u);
        A.u[2] = (mb.x > 0 ? 0x3F80u : 0u) | (mb.y > 0 ? 0x3F800000u : 0u);
        A.u[3] = (mb.z > 0 ? 0x3F80u : 0u) | (mb.w > 0 ? 0x3F800000u : 0u);

        // B-frags: emb channel r, same pixels (two swizzled b128 reads)
        float4 f0 = *(const float4*)&estage[wave][r][((cbase + 0) ^ rx) * 4];
        float4 f1 = *(const float4*)&estage[wave][r][((cbase + 1) ^ rx) * 4];
        union { bf16x8 v; unsigned u[4]; } Bf, B2;
        Bf.u[0] = pkbf(f0.x, f0.y);
        Bf.u[1] = pkbf(f0.z, f0.w);
        Bf.u[2] = pkbf(f1.x, f1.y);
        Bf.u[3] = pkbf(f1.z, f1.w);
        B2.u[0] = pkbf(f0.x * f0.x, f0.y * f0.y);
        B2.u[1] = pkbf(f0.z * f0.z, f0.w * f0.w);
        B2.u[2] = pkbf(f1.x * f1.x, f1.y * f1.y);
        B2.u[3] = pkbf(f1.z * f1.z, f1.w * f1.w);

        acc_s = __builtin_amdgcn_mfma_f32_16x16x32_bf16(A.v, Bf.v, acc_s, 0, 0, 0);
        acc_q = __builtin_amdgcn_mfma_f32_16x16x32_bf16(A.v, B2.v, acc_q, 0, 0, 0);
        acc_c = __builtin_amdgcn_mfma_f32_16x16x32_bf16(A.v, Bones.v, acc_c, 0, 0, 0);
    }

    // ---- block-level reduction (C/D: col=lane&15, row=quad*4+reg) ----
    #pragma unroll
    for (int j = 0; j < 4; ++j) {
        redbuf[wave][lane][j] = acc_s[j];
        redbuf[wave][lane][4 + j] = acc_q[j];
    }
    if (r == 0) {   // count cols identical; col-0 lanes own rows quad*4..+3
        #pragma unroll
        for (int reg = 0; reg < 4; ++reg) cnt_red[wave][quad * 4 + reg] = acc_c[reg];
    }
    __syncthreads();

    float* slice = ws + (size_t)(blockIdx.x & (NSLICE - 1)) * WSTOT;
    #pragma unroll
    for (int t = 0; t < 2; ++t) {
        const int fi = tid + t * THREADS;          // 0..511
        const int l2 = fi >> 3, j = fi & 7;
        float v = 0.f;
        #pragma unroll
        for (int w = 0; w < NWAVE; ++w) v += redbuf[w][l2][j];
        const int reg = j & 3, isq = j >> 2;
        const int krow = (l2 >> 4) * 4 + reg;
        const int ccol = l2 & 15;
        atomicAdd(&slice[64 + isq * 1024 + ((size_t)b * KK + krow) * CC + ccol], v);
    }
    if (tid < KK) {
        float ctot = 0.f;
        #pragma unroll
        for (int w = 0; w < NWAVE; ++w) ctot += cnt_red[w][tid];
        atomicAdd(&slice[b * KK + tid], ctot);
    }
}

__global__ __launch_bounds__(1024) void disc_finalize_kernel(
    const float* __restrict__ ws, float* __restrict__ out)
{
    __shared__ float red[WSTOT];             // slice-reduced [cnt|sum|sq]
    __shared__ float means[BB][KK][CC];
    __shared__ float partial[BB];
    const int tid = threadIdx.x;

    // vectorized slice reduction: 528 float4, 16 independent loads each
    for (int i4 = tid; i4 < WSTOT / 4; i4 += 1024) {
        float4 t = {0.f, 0.f, 0.f, 0.f};
        #pragma unroll
        for (int s = 0; s < NSLICE; ++s) {
            float4 v = *(const float4*)(ws + (size_t)s * WSTOT + 4 * i4);
            t.x += v.x; t.y += v.y; t.z += v.z; t.w += v.w;
        }
        *(float4*)(red + 4 * i4) = t;
    }
    __syncthreads();

    const float* red_cnt = red;
    const float* red_sum = red + 64;
    const float* red_sq  = red + 64 + 1024;

    const int b = tid >> 6;       // one wave per batch (waves 0..3 active)
    const int lane = tid & 63;
    const bool active = tid < 256;

    const float DELTA_PULL = 0.5f;
    const float DELTA_PUSH = 1.5f;
    const float EPS = 1e-6f;

    unsigned long long bal = 0ull;
    float M = 0.f, pull_b = 0.f;

    if (active) {
        float cntk = 0.f;
        bool valid = false;
        float pull_k = 0.f;
        if (lane < KK) {
            int k = lane;
            cntk = red_cnt[b * KK + k];
            valid = cntk > 0.f;
            float safe = fmaxf_(cntk, 1.f);
            float acc_sq = 0.f, acc_ss = 0.f;
            #pragma unroll
            for (int c = 0; c < CC; ++c) {
                float sv = red_sum[(b * KK + k) * CC + c];
                means[b][k][c] = sv / safe;
                acc_sq += red_sq[(b * KK + k) * CC + c];
                acc_ss += sv * sv;
            }
            if (valid) pull_k = (acc_sq - acc_ss / cntk) / (cntk + EPS);
        }

        bal = __ballot(lane < KK && valid);
        M = (float)__popcll(bal);

        float ps = pull_k;
        #pragma unroll
        for (int d = 32; d >= 1; d >>= 1) ps += __shfl_xor(ps, d, 64);
        pull_b = ps / fmaxf_(M, 1.f);
    }

    __syncthreads();

    if (active) {
        float push = 0.f;
        for (int t = lane; t < KK * KK; t += 64) {
            int i = t >> 4, j = t & 15;
            if (i < j && ((bal >> i) & 1ull) && ((bal >> j) & 1ull)) {
                float d2 = 1e-12f;
                #pragma unroll
                for (int c = 0; c < CC; ++c) {
                    float df = means[b][i][c] - means[b][j][c];
                    d2 = fmaf(df, df, d2);
                }
                float dist = sqrtf(d2);
                float h = fmaxf_(DELTA_PUSH - dist, 0.f);
                push += h * h;
            }
        }
        #pragma unroll
        for (int d = 32; d >= 1; d >>= 1) push += __shfl_xor(push, d, 64);

        if (lane == 0) {
            float npairs = M * (M - 1.f) * 0.5f;
            float push_b = (M > 1.f) ? push / fmaxf_(npairs, 1.f) : 0.f;
            partial[b] = DELTA_PULL * pull_b + push_b;
        }
    }
    __syncthreads();
    if (tid == 0) {
        out[0] = (partial[0] + partial[1] + partial[2] + partial[3]) * 0.25f;
    }
}

extern "C" void kernel_launch(void* const* d_in, const int* in_sizes, int n_in,
                              void* d_out, int out_size, void* d_ws, size_t ws_size,
                              hipStream_t stream) {
    const float* emb = (const float*)d_in[0];
    const int* masks = (const int*)d_in[1];
    float* ws = (float*)d_ws;

    hipMemsetAsync(d_ws, 0, NSLICE * WSTOT * sizeof(float), stream);

    dim3 grid(BB * NTILES);
    disc_mfma_kernel<<<grid, THREADS, 0, stream>>>(emb, masks, ws);
    disc_finalize_kernel<<<1, 1024, 0, stream>>>(ws, (float*)d_out);
}